// Round 8
// baseline (456.972 us; speedup 1.0000x reference)
//
#include <hip/hip_runtime.h>
#include <math.h>

// Problem constants (from setup_inputs)
constexpr int kB = 16;      // batch
constexpr int kD = 2048;    // rep dim
constexpr int kV = 504;     // verbs
constexpr int kR = 190;     // roles
constexpr int kH = 32;      // hidden
constexpr int kMR = 6;      // max roles/verb
constexpr int kG = 2000;    // group size
constexpr int kL = 3;       // attn layers
constexpr int kNH = 4;      // heads
constexpr int kHD = 8;      // head dim
constexpr int kC1 = kV + kR * kH;   // 6584 fused GEMM columns
constexpr int kNDS = 8;             // d-splits for k1a
constexpr int kDCH = kD / kNDS;     // 256

// k2 qkv row stride: 100 words = 400 B = 0 mod 16 -> EVERY row 16B-aligned
// (97 left odd rows misaligned -> scalar LDS reads). Row holds q|k|v (96) + pad.
constexpr int kQS = 100;

// k3 role-major params
constexpr int kMAXP = 64;   // max (v,s) pairs stored per role (mean 9.3)
constexpr int kGCH = 500;   // g-chunk length (4 x 500 = 2000 = kG)
constexpr int kGC = 4;      // number of g chunks

// ws layout (float offsets).  REST is time-shared:
//   phase 1 (k1a/k1b): PART partials (kNDS*kB*kC1 = 842752 floats)
//   phase 2 (k0/k3a/k3b): PM/PS/PI partials + role lists (~593K floats)
constexpr size_t WS_NODE = 0;                           // kB*kR*kH      = 97280
constexpr size_t WS_X    = WS_NODE + (size_t)kB*kR*kH;  // kV*kMR*kB*kH  = 1548288
constexpr size_t WS_REST = WS_X + (size_t)kV*kMR*kB*kH;
constexpr size_t WS_PART = WS_REST;
constexpr size_t WS_PM   = WS_REST;                               // kV*kMR*kB*kGC
constexpr size_t WS_PS   = WS_PM + (size_t)kV*kMR*kB*kGC;
constexpr size_t WS_PI   = WS_PS + (size_t)kV*kMR*kB*kGC;
constexpr size_t WS_CNT  = WS_PI + (size_t)kV*kMR*kB*kGC;         // kR ints
constexpr size_t WS_PAIR = WS_CNT + kR;                           // kR*kMAXP ints

// out layout (float offsets), tuple concatenated flat
constexpr size_t O_VPOT = 0;                       // (B,V)
constexpr size_t O_NORM = O_VPOT + (size_t)kB*kV;  // (B,)
constexpr size_t O_VMAX = O_NORM + kB;             // (B,V)
constexpr size_t O_VRN  = O_VMAX + (size_t)kB*kV;  // (B,V,MR)
constexpr size_t O_VRM  = O_VRN + (size_t)kB*kV*kMR;
constexpr size_t O_VRI  = O_VRM + (size_t)kB*kV*kMR;

__device__ inline float dot4(float4 a, float4 w, float acc) {
  return fmaf(a.x, w.x, fmaf(a.y, w.y, fmaf(a.z, w.z, fmaf(a.w, w.w, acc))));
}

// ---------------- k1a: rep @ [W_v | W_r], d-split partials ----------------
__global__ __launch_bounds__(256) void k1a(const float* __restrict__ rep,
                                           const float* __restrict__ Wv,
                                           const float* __restrict__ Wr,
                                           float* __restrict__ part) {
  __shared__ float rl[kB][kDCH];
  const int tid = threadIdx.x;
  const int col = blockIdx.x * 256 + tid;
  const int d0 = blockIdx.y * kDCH;
  for (int i = tid; i < kB * kDCH; i += 256) {
    int b = i >> 8, dd = i & (kDCH - 1);
    rl[b][dd] = rep[b * kD + d0 + dd];
  }
  __syncthreads();
  if (col >= kC1) return;
  const float* Wp;
  int stride;
  if (col < kV) { Wp = Wv + (size_t)d0 * kV + col; stride = kV; }
  else          { Wp = Wr + (size_t)d0 * (kR*kH) + (col - kV); stride = kR*kH; }
  float acc[kB];
#pragma unroll
  for (int b = 0; b < kB; b++) acc[b] = 0.f;
  for (int dd = 0; dd < kDCH; dd++) {
    float w = Wp[(size_t)dd * stride];
#pragma unroll
    for (int b = 0; b < kB; b++) acc[b] += rl[b][dd] * w;
  }
  float* p = part + (size_t)(blockIdx.y * kB) * kC1 + col;
#pragma unroll
  for (int b = 0; b < kB; b++) p[(size_t)b * kC1] = acc[b];
}

// ---------------- k1b: reduce partials + bias, scatter to out/node -------
__global__ __launch_bounds__(256) void k1b(const float* __restrict__ part,
                                           const float* __restrict__ bv,
                                           const float* __restrict__ br,
                                           float* __restrict__ out,
                                           float* __restrict__ node) {
  int idx = blockIdx.x * 256 + threadIdx.x;
  if (idx >= kB * kC1) return;
  int b = idx / kC1, col = idx % kC1;
  float s = 0.f;
#pragma unroll
  for (int ds = 0; ds < kNDS; ds++) s += part[(size_t)(ds * kB + b) * kC1 + col];
  if (col < kV) out[O_VPOT + (size_t)b * kV + col] = s + bv[col];
  else          node[(size_t)b * (kR*kH) + (col - kV)] = s + br[col - kV];
}

// ---------------- k0: build role -> pair lists ---------------------------
__global__ __launch_bounds__(256) void k0(const int* __restrict__ verb_roles,
                                          int* __restrict__ cnt,
                                          int* __restrict__ pairs) {
  const int tid = threadIdx.x;
  for (int i = tid; i < kR; i += 256) cnt[i] = 0;
  __syncthreads();
  for (int i = tid; i < kV * kMR; i += 256) {
    int r = verb_roles[i];
    if (r >= 0) {
      int pos = atomicAdd(&cnt[r], 1);
      if (pos < kMAXP) pairs[r * kMAXP + pos] = i;   // i = v*kMR + s
    }
  }
}

// ---------------- k2: per-verb 3-layer MHA, spill-free 2-row tiling ------
// 384 threads = 6 waves. thread = (rp = tid>>3, oct = tid&7), owns rows
// {2rp, 2rp+1}. x lives in xr[2][8] float4 (64 VGPR) — the ONLY big array;
// out-proj reuses xr for the o-row (x is dead by then) and stages new-x
// through qkv's dead K-slot. No orow[] -> no scratch spill (round-7 bug:
// 196MB HBM spill traffic). kQS=100 -> all qkv rows 16B-aligned (b128).
__global__ __launch_bounds__(384, 3) void k2(const float* __restrict__ node,
                                             const int* __restrict__ verb_roles,
                                             const float* __restrict__ in_w,
                                             const float* __restrict__ in_b,
                                             const float* __restrict__ out_w,
                                             const float* __restrict__ out_b,
                                             float* __restrict__ xout) {
  __shared__ float wi[96 * 44];
  __shared__ float wo[32 * 44];
  __shared__ float bi[96];
  __shared__ float bo[32];
  __shared__ float qkv[96 * kQS];
  __shared__ int roles[kMR];
  const int v = blockIdx.x;
  const int tid = threadIdx.x;
  if (tid < kMR) roles[tid] = verb_roles[v * kMR + tid];
  __syncthreads();
  const int rp = tid >> 3, oct = tid & 7;
  const int row0 = 2 * rp, row1 = row0 + 1;
  const int s0 = row0 >> 4, b0 = row0 & 15;
  const int s1 = row1 >> 4, b1 = row1 & 15;
  float4 xr[2][8];
  {
    int r0 = roles[s0] < 0 ? 0 : roles[s0];
    int r1 = roles[s1] < 0 ? 0 : roles[s1];
    const float4* xp0 = (const float4*)(node + (size_t)b0 * (kR*kH) + r0 * kH);
    const float4* xp1 = (const float4*)(node + (size_t)b1 * (kR*kH) + r1 * kH);
#pragma unroll
    for (int j = 0; j < 8; j++) { xr[0][j] = xp0[j]; xr[1][j] = xp1[j]; }
  }
  for (int l = 0; l < kL; l++) {
    for (int i = tid; i < 96 * 32; i += 384) wi[(i >> 5) * 44 + (i & 31)] = in_w[(size_t)l*96*32 + i];
    for (int i = tid; i < 32 * 32; i += 384) wo[(i >> 5) * 44 + (i & 31)] = out_w[(size_t)l*32*32 + i];
    if (tid < 96) bi[tid] = in_b[l*96 + tid];
    else if (tid < 128) bo[tid - 96] = out_b[l*32 + (tid - 96)];
    __syncthreads();
    // ---- QKV: 12 interleaved cols x 2 rows per thread
#pragma unroll
    for (int fi = 0; fi < 12; fi++) {
      const int f = oct + 8 * fi;
      const float4* wr = (const float4*)&wi[f * 44];
      float a0 = 0.f, a1 = 0.f, a2 = 0.f, a3 = 0.f;
      float c0 = 0.f, c1 = 0.f, c2 = 0.f, c3 = 0.f;
#pragma unroll
      for (int j = 0; j < 8; j += 4) {
        float4 w0 = wr[j], w1 = wr[j+1], w2 = wr[j+2], w3 = wr[j+3];
        a0 = dot4(xr[0][j],   w0, a0);  c0 = dot4(xr[1][j],   w0, c0);
        a1 = dot4(xr[0][j+1], w1, a1);  c1 = dot4(xr[1][j+1], w1, c1);
        a2 = dot4(xr[0][j+2], w2, a2);  c2 = dot4(xr[1][j+2], w2, c2);
        a3 = dot4(xr[0][j+3], w3, a3);  c3 = dot4(xr[1][j+3], w3, c3);
      }
      const float bf = bi[f];
      qkv[row0 * kQS + f] = ((a0 + a1) + (a2 + a3)) + bf;
      qkv[row1 * kQS + f] = ((c0 + c1) + (c2 + c3)) + bf;
    }
    __syncthreads();
    // ---- attention: unit = tid = (us, uh, ub); reads/writes b128-aligned
    {
      const int us = tid >> 6, uh = (tid >> 4) & 3, ub = tid & 15;
      const int base = (us * 16 + ub) * kQS + uh * 8;
      float q[8];
#pragma unroll
      for (int d = 0; d < 8; d++) q[d] = qkv[base + d] * 0.35355339059327373f;
      float sc[kMR];
      float mx = -INFINITY;
#pragma unroll
      for (int t = 0; t < kMR; t++) {
        const int kb = (t * 16 + ub) * kQS + 32 + uh * 8;
        float a = 0.f;
#pragma unroll
        for (int d = 0; d < 8; d++) a = fmaf(q[d], qkv[kb + d], a);
        sc[t] = a;
        if (roles[t] >= 0 && a > mx) mx = a;
      }
      float sum = 0.f;
#pragma unroll
      for (int t = 0; t < kMR; t++) {
        float e = (roles[t] >= 0) ? __expf(sc[t] - mx) : 0.f;
        sc[t] = e; sum += e;
      }
      const float inv = 1.f / sum;
      float o[8];
#pragma unroll
      for (int d = 0; d < 8; d++) o[d] = 0.f;
#pragma unroll
      for (int t = 0; t < kMR; t++) {
        const float w = sc[t] * inv;
        const int vb = (t * 16 + ub) * kQS + 64 + uh * 8;
#pragma unroll
        for (int d = 0; d < 8; d++) o[d] = fmaf(w, qkv[vb + d], o[d]);
      }
#pragma unroll
      for (int d = 0; d < 8; d++) qkv[base + d] = o[d];  // own q-slot
    }
    __syncthreads();
    // ---- out-proj: o-row -> xr (x is dead), 4 cols x 2 rows, new-x via K-slot
    {
      const float4* o0 = (const float4*)&qkv[row0 * kQS];
      const float4* o1 = (const float4*)&qkv[row1 * kQS];
#pragma unroll
      for (int j = 0; j < 8; j++) { xr[0][j] = o0[j]; xr[1][j] = o1[j]; }
    }
    float acc0[4], acc1[4];
#pragma unroll
    for (int ci = 0; ci < 4; ci++) {
      const int c2 = oct + 8 * ci;
      const float4* wr = (const float4*)&wo[c2 * 44];
      float a0 = 0.f, a1 = 0.f, a2 = 0.f, a3 = 0.f;
      float d0 = 0.f, d1 = 0.f, d2 = 0.f, d3 = 0.f;
#pragma unroll
      for (int j = 0; j < 8; j += 4) {
        float4 w0 = wr[j], w1 = wr[j+1], w2 = wr[j+2], w3 = wr[j+3];
        a0 = dot4(xr[0][j],   w0, a0);  d0 = dot4(xr[1][j],   w0, d0);
        a1 = dot4(xr[0][j+1], w1, a1);  d1 = dot4(xr[1][j+1], w1, d1);
        a2 = dot4(xr[0][j+2], w2, a2);  d2 = dot4(xr[1][j+2], w2, d2);
        a3 = dot4(xr[0][j+3], w3, a3);  d3 = dot4(xr[1][j+3], w3, d3);
      }
      const float bc = bo[c2];
      acc0[ci] = ((a0 + a1) + (a2 + a3)) + bc;
      acc1[ci] = ((d0 + d1) + (d2 + d3)) + bc;
    }
#pragma unroll
    for (int ci = 0; ci < 4; ci++) {
      qkv[row0 * kQS + 32 + oct + 8 * ci] = acc0[ci];   // dead K-slot
      qkv[row1 * kQS + 32 + oct + 8 * ci] = acc1[ci];
    }
    __syncthreads();
    {
      const float4* n0 = (const float4*)&qkv[row0 * kQS + 32];
      const float4* n1 = (const float4*)&qkv[row1 * kQS + 32];
#pragma unroll
      for (int j = 0; j < 8; j++) { xr[0][j] = n0[j]; xr[1][j] = n1[j]; }
    }
    if (l < kL - 1) __syncthreads();  // reload done before next staging/QKV writes
  }
  // final write: thread's oct picks float4 #oct of each of its 2 rows
  {
    float4* d0p = (float4*)(xout + ((size_t)v * 96 + row0) * kH);
    float4* d1p = (float4*)(xout + ((size_t)v * 96 + row1) * kH);
    d0p[oct] = xr[0][oct];
    d1p[oct] = xr[1][oct];
  }
}

// ---------------- k3a: role-major logits, 2 pairs/thread -----------------
// block = (role r, g-chunk gc); 256 threads = 4 waves x (16 b x 4 slots).
// Wave w owns g-slice [125w,125w+125); thread handles 2 pairs so each
// 8x-float4 W-row read feeds 64 FMA. W rows stride-36 in LDS (16B aligned).
// g-loop unrolled x2 so the compiler pipelines next-g LDS reads under FMA.
__global__ __launch_bounds__(256) void k3a(const float* __restrict__ xw,
                                           const int* __restrict__ cnt,
                                           const int* __restrict__ pairs,
                                           const int* __restrict__ group_len,
                                           const float* __restrict__ Wn,
                                           const float* __restrict__ bn,
                                           float* __restrict__ PM,
                                           float* __restrict__ PS,
                                           float* __restrict__ PI) {
  __shared__ float Wl[kGCH * 36];
  __shared__ float Bl[kGCH];
  __shared__ float mbM[4][8][kB], mbS[4][8][kB], mbI[4][8][kB];
  const int r = blockIdx.x, gc = blockIdx.y;
  const int glen = group_len[r];
  const int g0 = gc * kGCH;
  if (g0 >= glen) return;
  int c = cnt[r]; if (c > kMAXP) c = kMAXP;
  if (c == 0) return;
  const int gn = (kGCH < glen - g0) ? kGCH : (glen - g0);
  const int tid = threadIdx.x;
  const float* W = Wn + (size_t)r * kH * kG + g0;
  const float* bias = bn + (size_t)r * kG + g0;
  for (int g = tid; g < gn; g += 256) {
#pragma unroll
    for (int h = 0; h < kH; h++) Wl[g * 36 + h] = W[(size_t)h * kG + g];
    Bl[g] = bias[g];
  }
  __syncthreads();
  const int wave = tid >> 6, lane = tid & 63;
  const int b = lane & 15, slot = lane >> 4;
  int gw0 = wave * 125, gw1 = gw0 + 125;
  gw0 = (gw0 < gn) ? gw0 : gn;
  gw1 = (gw1 < gn) ? gw1 : gn;
  const int nq = (c + 7) >> 3;
  for (int q = 0; q < nq; q++) {
    const int p0 = 8 * q + 2 * slot, p1 = p0 + 1;
    const bool v0 = p0 < c, v1 = p1 < c;
    const int pr0 = pairs[r * kMAXP + (v0 ? p0 : 0)];
    const int pr1 = pairs[r * kMAXP + (v1 ? p1 : 0)];
    float4 x0[8], x1[8];
    {
      const float4* xp0 = (const float4*)(xw + ((size_t)pr0 * kB + b) * kH);
      const float4* xp1 = (const float4*)(xw + ((size_t)pr1 * kB + b) * kH);
#pragma unroll
      for (int j = 0; j < 8; j++) { x0[j] = xp0[j]; x1[j] = xp1[j]; }
    }
    float m0 = -INFINITY, s0 = 0.f, m1 = -INFINITY, s1 = 0.f;
    int i0 = 0, i1 = 0;
#pragma unroll 2
    for (int g = gw0; g < gw1; g++) {
      const float4* wr = (const float4*)&Wl[g * 36];
      const float bg = Bl[g];
      float a0 = 0.f, a1 = 0.f, a2 = 0.f, a3 = 0.f;
      float c0 = 0.f, c1 = 0.f, c2 = 0.f, c3 = 0.f;
#pragma unroll
      for (int j = 0; j < 8; j += 4) {
        float4 w0 = wr[j], w1 = wr[j+1], w2 = wr[j+2], w3 = wr[j+3];
        a0 = dot4(x0[j],   w0, a0);  c0 = dot4(x1[j],   w0, c0);
        a1 = dot4(x0[j+1], w1, a1);  c1 = dot4(x1[j+1], w1, c1);
        a2 = dot4(x0[j+2], w2, a2);  c2 = dot4(x1[j+2], w2, c2);
        a3 = dot4(x0[j+3], w3, a3);  c3 = dot4(x1[j+3], w3, c3);
      }
      const float acc0 = ((a0 + a1) + (a2 + a3)) + bg;
      const float acc1 = ((c0 + c1) + (c2 + c3)) + bg;
      {
        float d = acc0 - m0; bool gt = d > 0.f;
        float e = __expf(gt ? -d : d);
        s0 = gt ? fmaf(s0, e, 1.f) : s0 + e;
        i0 = gt ? g0 + g : i0;  m0 = gt ? acc0 : m0;
      }
      {
        float d = acc1 - m1; bool gt = d > 0.f;
        float e = __expf(gt ? -d : d);
        s1 = gt ? fmaf(s1, e, 1.f) : s1 + e;
        i1 = gt ? g0 + g : i1;  m1 = gt ? acc1 : m1;
      }
    }
    mbM[wave][2*slot][b]   = v0 ? m0 : -INFINITY;
    mbS[wave][2*slot][b]   = s0;
    mbI[wave][2*slot][b]   = (float)i0;
    mbM[wave][2*slot+1][b] = v1 ? m1 : -INFINITY;
    mbS[wave][2*slot+1][b] = s1;
    mbI[wave][2*slot+1][b] = (float)i1;
    __syncthreads();
    if (tid < 128) {
      const int pl = tid >> 4, bb = tid & 15;
      const int pg = 8 * q + pl;
      if (pg < c) {
        float M = -INFINITY, S = 0.f; int I = 0;
#pragma unroll
        for (int w = 0; w < 4; w++) {
          float om = mbM[w][pl][bb];
          float os = mbS[w][pl][bb];
          int oi = (int)mbI[w][pl][bb];
          if (om != -INFINITY) {
            if (M == -INFINITY)      { M = om; S = os; I = oi; }
            else if (om > M)         { S = S * __expf(M - om) + os; M = om; I = oi; }
            else if (om < M)         { S = S + os * __expf(om - M); }
            else                     { S += os; I = (oi < I) ? oi : I; }
          }
        }
        const int pr2 = pairs[r * kMAXP + pg];
        size_t o = ((size_t)pr2 * kB + bb) * kGC + gc;
        PM[o] = M; PS[o] = S; PI[o] = (float)I;
      }
    }
    __syncthreads();
  }
}

// ---------------- k3b: merge g-chunk partials -> outputs -----------------
__device__ inline void lse_merge(float& m, float& s, int& i, float om, float os, int oi) {
  if (om == -INFINITY) return;
  if (m == -INFINITY) { m = om; s = os; i = oi; return; }
  if (om > m)       { s = s * __expf(m - om) + os; m = om; i = oi; }
  else if (om < m)  { s = s + os * __expf(om - m); }
  else              { s += os; i = (oi < i) ? oi : i; }
}

__global__ __launch_bounds__(256) void k3b(const int* __restrict__ verb_roles,
                                           const int* __restrict__ group_len,
                                           const float* __restrict__ PM,
                                           const float* __restrict__ PS,
                                           const float* __restrict__ PI,
                                           float* __restrict__ out) {
  const int idx = blockIdx.x * 256 + threadIdx.x;
  if (idx >= kV * kMR * kB) return;
  const int pr = idx >> 4;        // v*kMR + s
  const int b = idx & 15;
  const int v = pr / kMR, s = pr % kMR;
  const size_t o = ((size_t)b * kV + v) * kMR + s;
  const int r = verb_roles[pr];
  if (r < 0) {
    out[O_VRN + o] = 0.f; out[O_VRM + o] = 0.f; out[O_VRI + o] = 0.f;
    return;
  }
  const int glen = group_len[r];
  const int ngc = (glen + kGCH - 1) / kGCH;
  float M = -INFINITY, S = 0.f; int I = 0;
  for (int gc = 0; gc < ngc; gc++) {
    size_t po = ((size_t)pr * kB + b) * kGC + gc;
    lse_merge(M, S, I, PM[po], PS[po], (int)PI[po]);
  }
  out[O_VRN + o] = M + logf(S);
  out[O_VRM + o] = M;
  out[O_VRI + o] = (float)I;
}

// ---------------- k4: v_max, v_marginal LSE -> norm ----------------------
__global__ __launch_bounds__(256) void k4(float* __restrict__ out) {
  const int b = blockIdx.x;
  const int tid = threadIdx.x;
  float M = -INFINITY, S = 0.f;
  for (int v = tid; v < kV; v += 256) {
    float sm = 0.f, sx = 0.f;
#pragma unroll
    for (int s = 0; s < kMR; s++) {
      size_t o = ((size_t)b * kV + v) * kMR + s;
      sm += out[O_VRN + o];
      sx += out[O_VRM + o];
    }
    float vp = out[O_VPOT + (size_t)b * kV + v];
    float vm = sm + vp;
    out[O_VMAX + (size_t)b * kV + v] = sx + vp;
    float nm = fmaxf(M, vm);
    S = S * __expf(M - nm) + __expf(vm - nm);
    M = nm;
  }
#pragma unroll
  for (int off = 1; off < 64; off <<= 1) {
    float om = __shfl_xor(M, off);
    float os = __shfl_xor(S, off);
    if (om != -INFINITY) {
      if (M == -INFINITY) { M = om; S = os; }
      else if (om > M) { S = S * __expf(M - om) + os; M = om; }
      else { S += os * __expf(om - M); }
    }
  }
  __shared__ float rm2[4], rs2[4];
  const int wave = tid >> 6, lane = tid & 63;
  if (lane == 0) { rm2[wave] = M; rs2[wave] = S; }
  __syncthreads();
  if (tid == 0) {
    float Mm = rm2[0], Ss = rs2[0];
    for (int w = 1; w < 4; w++) {
      float om = rm2[w], os = rs2[w];
      if (om > Mm) { Ss = Ss * __expf(Mm - om) + os; Mm = om; }
      else { Ss += os * __expf(om - Mm); }
    }
    out[O_NORM + b] = Mm + logf(Ss);
  }
}

extern "C" void kernel_launch(void* const* d_in, const int* in_sizes, int n_in,
                              void* d_out, int out_size, void* d_ws, size_t ws_size,
                              hipStream_t stream) {
  const float* rep = (const float*)d_in[0];
  const float* Wv  = (const float*)d_in[1];
  const float* bv  = (const float*)d_in[2];
  const float* Wr  = (const float*)d_in[3];
  const float* br  = (const float*)d_in[4];
  const float* aiw = (const float*)d_in[5];
  const float* aib = (const float*)d_in[6];
  const float* aow = (const float*)d_in[7];
  const float* aob = (const float*)d_in[8];
  const float* Wn  = (const float*)d_in[9];
  const float* bnn = (const float*)d_in[10];
  const int* vrl   = (const int*)d_in[11];
  const int* gl    = (const int*)d_in[12];
  float* out = (float*)d_out;
  float* ws  = (float*)d_ws;
  int* icnt  = (int*)(ws + WS_CNT);
  int* ipair = (int*)(ws + WS_PAIR);

  k1a<<<dim3((kC1 + 255) / 256, kNDS), 256, 0, stream>>>(rep, Wv, Wr, ws + WS_PART);
  k1b<<<(kB * kC1 + 255) / 256, 256, 0, stream>>>(ws + WS_PART, bv, br, out, ws + WS_NODE);
  k0<<<1, 256, 0, stream>>>(vrl, icnt, ipair);
  k2<<<kV, 384, 0, stream>>>(ws + WS_NODE, vrl, aiw, aib, aow, aob, ws + WS_X);
  k3a<<<dim3(kR, kGC), 256, 0, stream>>>(ws + WS_X, icnt, ipair, gl, Wn, bnn,
                                         ws + WS_PM, ws + WS_PS, ws + WS_PI);
  k3b<<<(kV * kMR * kB + 255) / 256, 256, 0, stream>>>(vrl, gl, ws + WS_PM, ws + WS_PS,
                                                       ws + WS_PI, out);
  k4<<<kB, 256, 0, stream>>>(out);
}

// Round 9
// 226.971 us; speedup vs baseline: 2.0133x; 2.0133x over previous
//
#include <hip/hip_runtime.h>
#include <math.h>

// Problem constants (from setup_inputs)
constexpr int kB = 16;      // batch
constexpr int kD = 2048;    // rep dim
constexpr int kV = 504;     // verbs
constexpr int kR = 190;     // roles
constexpr int kH = 32;      // hidden
constexpr int kMR = 6;      // max roles/verb
constexpr int kG = 2000;    // group size
constexpr int kL = 3;       // attn layers
constexpr int kNH = 4;      // heads
constexpr int kHD = 8;      // head dim
constexpr int kC1 = kV + kR * kH;   // 6584 fused GEMM columns
constexpr int kNDS = 8;             // d-splits for k1a
constexpr int kDCH = kD / kNDS;     // 256

// k2 qkv row stride: 100 words = 400 B = 0 mod 16 -> EVERY row 16B-aligned.
constexpr int kQS = 100;

// k3 role-major params
constexpr int kMAXP = 64;   // max (v,s) pairs stored per role (mean 9.3)
constexpr int kGCH = 500;   // g-chunk length (4 x 500 = 2000 = kG)
constexpr int kGC = 4;      // number of g chunks

// ws layout (float offsets).  REST is time-shared:
//   phase 1 (k1a/k1b): PART partials (kNDS*kB*kC1 = 842752 floats)
//   phase 2 (k0/k3a/k3b): PM/PS/PI partials + role lists (~593K floats)
constexpr size_t WS_NODE = 0;                           // kB*kR*kH      = 97280
constexpr size_t WS_X    = WS_NODE + (size_t)kB*kR*kH;  // kV*kMR*kB*kH  = 1548288
constexpr size_t WS_REST = WS_X + (size_t)kV*kMR*kB*kH;
constexpr size_t WS_PART = WS_REST;
constexpr size_t WS_PM   = WS_REST;                               // kV*kMR*kB*kGC
constexpr size_t WS_PS   = WS_PM + (size_t)kV*kMR*kB*kGC;
constexpr size_t WS_PI   = WS_PS + (size_t)kV*kMR*kB*kGC;
constexpr size_t WS_CNT  = WS_PI + (size_t)kV*kMR*kB*kGC;         // kR ints
constexpr size_t WS_PAIR = WS_CNT + kR;                           // kR*kMAXP ints

// out layout (float offsets), tuple concatenated flat
constexpr size_t O_VPOT = 0;                       // (B,V)
constexpr size_t O_NORM = O_VPOT + (size_t)kB*kV;  // (B,)
constexpr size_t O_VMAX = O_NORM + kB;             // (B,V)
constexpr size_t O_VRN  = O_VMAX + (size_t)kB*kV;  // (B,V,MR)
constexpr size_t O_VRM  = O_VRN + (size_t)kB*kV*kMR;
constexpr size_t O_VRI  = O_VRM + (size_t)kB*kV*kMR;

__device__ inline float dot4(float4 a, float4 w, float acc) {
  return fmaf(a.x, w.x, fmaf(a.y, w.y, fmaf(a.z, w.z, fmaf(a.w, w.w, acc))));
}

// ---------------- k1a: rep @ [W_v | W_r], d-split partials ----------------
__global__ __launch_bounds__(256) void k1a(const float* __restrict__ rep,
                                           const float* __restrict__ Wv,
                                           const float* __restrict__ Wr,
                                           float* __restrict__ part) {
  __shared__ float rl[kB][kDCH];
  const int tid = threadIdx.x;
  const int col = blockIdx.x * 256 + tid;
  const int d0 = blockIdx.y * kDCH;
  for (int i = tid; i < kB * kDCH; i += 256) {
    int b = i >> 8, dd = i & (kDCH - 1);
    rl[b][dd] = rep[b * kD + d0 + dd];
  }
  __syncthreads();
  if (col >= kC1) return;
  const float* Wp;
  int stride;
  if (col < kV) { Wp = Wv + (size_t)d0 * kV + col; stride = kV; }
  else          { Wp = Wr + (size_t)d0 * (kR*kH) + (col - kV); stride = kR*kH; }
  float acc[kB];
#pragma unroll
  for (int b = 0; b < kB; b++) acc[b] = 0.f;
  for (int dd = 0; dd < kDCH; dd++) {
    float w = Wp[(size_t)dd * stride];
#pragma unroll
    for (int b = 0; b < kB; b++) acc[b] += rl[b][dd] * w;
  }
  float* p = part + (size_t)(blockIdx.y * kB) * kC1 + col;
#pragma unroll
  for (int b = 0; b < kB; b++) p[(size_t)b * kC1] = acc[b];
}

// ---------------- k1b: reduce partials + bias, scatter to out/node -------
__global__ __launch_bounds__(256) void k1b(const float* __restrict__ part,
                                           const float* __restrict__ bv,
                                           const float* __restrict__ br,
                                           float* __restrict__ out,
                                           float* __restrict__ node) {
  int idx = blockIdx.x * 256 + threadIdx.x;
  if (idx >= kB * kC1) return;
  int b = idx / kC1, col = idx % kC1;
  float s = 0.f;
#pragma unroll
  for (int ds = 0; ds < kNDS; ds++) s += part[(size_t)(ds * kB + b) * kC1 + col];
  if (col < kV) out[O_VPOT + (size_t)b * kV + col] = s + bv[col];
  else          node[(size_t)b * (kR*kH) + (col - kV)] = s + br[col - kV];
}

// ---------------- k0: build role -> pair lists ---------------------------
__global__ __launch_bounds__(256) void k0(const int* __restrict__ verb_roles,
                                          int* __restrict__ cnt,
                                          int* __restrict__ pairs) {
  const int tid = threadIdx.x;
  for (int i = tid; i < kR; i += 256) cnt[i] = 0;
  __syncthreads();
  for (int i = tid; i < kV * kMR; i += 256) {
    int r = verb_roles[i];
    if (r >= 0) {
      int pos = atomicAdd(&cnt[r], 1);
      if (pos < kMAXP) pairs[r * kMAXP + pos] = i;   // i = v*kMR + s
    }
  }
}

// ---------------- k2: per-verb 3-layer MHA, spill-free 2-row tiling ------
// 384 threads = 6 waves. thread = (rp = tid>>3, oct = tid&7), owns rows
// {2rp, 2rp+1}. x lives in xr[2][8] float4 — ALL indexing compile-time
// (rule #20: runtime-indexed register arrays go to scratch; the round-7/8
// regression was `xr[0][oct]` in the final write -> whole array in scratch,
// 374MB HBM spill). Final output now copied cooperatively from qkv's K-slot
// in LDS; no register array is ever runtime-indexed.
__global__ __launch_bounds__(384) void k2(const float* __restrict__ node,
                                          const int* __restrict__ verb_roles,
                                          const float* __restrict__ in_w,
                                          const float* __restrict__ in_b,
                                          const float* __restrict__ out_w,
                                          const float* __restrict__ out_b,
                                          float* __restrict__ xout) {
  __shared__ float wi[96 * 44];
  __shared__ float wo[32 * 44];
  __shared__ float bi[96];
  __shared__ float bo[32];
  __shared__ float qkv[96 * kQS];
  __shared__ int roles[kMR];
  const int v = blockIdx.x;
  const int tid = threadIdx.x;
  if (tid < kMR) roles[tid] = verb_roles[v * kMR + tid];
  __syncthreads();
  const int rp = tid >> 3, oct = tid & 7;
  const int row0 = 2 * rp, row1 = row0 + 1;
  const int s0 = row0 >> 4, b0 = row0 & 15;
  const int s1 = row1 >> 4, b1 = row1 & 15;
  float4 xr[2][8];
  {
    int r0 = roles[s0] < 0 ? 0 : roles[s0];
    int r1 = roles[s1] < 0 ? 0 : roles[s1];
    const float4* xp0 = (const float4*)(node + (size_t)b0 * (kR*kH) + r0 * kH);
    const float4* xp1 = (const float4*)(node + (size_t)b1 * (kR*kH) + r1 * kH);
#pragma unroll
    for (int j = 0; j < 8; j++) { xr[0][j] = xp0[j]; xr[1][j] = xp1[j]; }
  }
  for (int l = 0; l < kL; l++) {
    for (int i = tid; i < 96 * 32; i += 384) wi[(i >> 5) * 44 + (i & 31)] = in_w[(size_t)l*96*32 + i];
    for (int i = tid; i < 32 * 32; i += 384) wo[(i >> 5) * 44 + (i & 31)] = out_w[(size_t)l*32*32 + i];
    if (tid < 96) bi[tid] = in_b[l*96 + tid];
    else if (tid < 128) bo[tid - 96] = out_b[l*32 + (tid - 96)];
    __syncthreads();
    // ---- QKV: 12 interleaved cols x 2 rows per thread
#pragma unroll
    for (int fi = 0; fi < 12; fi++) {
      const int f = oct + 8 * fi;
      const float4* wr = (const float4*)&wi[f * 44];
      float a0 = 0.f, a1 = 0.f, a2 = 0.f, a3 = 0.f;
      float c0 = 0.f, c1 = 0.f, c2 = 0.f, c3 = 0.f;
#pragma unroll
      for (int j = 0; j < 8; j += 4) {
        float4 w0 = wr[j], w1 = wr[j+1], w2 = wr[j+2], w3 = wr[j+3];
        a0 = dot4(xr[0][j],   w0, a0);  c0 = dot4(xr[1][j],   w0, c0);
        a1 = dot4(xr[0][j+1], w1, a1);  c1 = dot4(xr[1][j+1], w1, c1);
        a2 = dot4(xr[0][j+2], w2, a2);  c2 = dot4(xr[1][j+2], w2, c2);
        a3 = dot4(xr[0][j+3], w3, a3);  c3 = dot4(xr[1][j+3], w3, c3);
      }
      const float bf = bi[f];
      qkv[row0 * kQS + f] = ((a0 + a1) + (a2 + a3)) + bf;
      qkv[row1 * kQS + f] = ((c0 + c1) + (c2 + c3)) + bf;
    }
    __syncthreads();
    // ---- attention: unit = tid = (us, uh, ub); reads/writes b128-aligned
    {
      const int us = tid >> 6, uh = (tid >> 4) & 3, ub = tid & 15;
      const int base = (us * 16 + ub) * kQS + uh * 8;
      float q[8];
#pragma unroll
      for (int d = 0; d < 8; d++) q[d] = qkv[base + d] * 0.35355339059327373f;
      float sc[kMR];
      float mx = -INFINITY;
#pragma unroll
      for (int t = 0; t < kMR; t++) {
        const int kb = (t * 16 + ub) * kQS + 32 + uh * 8;
        float a = 0.f;
#pragma unroll
        for (int d = 0; d < 8; d++) a = fmaf(q[d], qkv[kb + d], a);
        sc[t] = a;
        if (roles[t] >= 0 && a > mx) mx = a;
      }
      float sum = 0.f;
#pragma unroll
      for (int t = 0; t < kMR; t++) {
        float e = (roles[t] >= 0) ? __expf(sc[t] - mx) : 0.f;
        sc[t] = e; sum += e;
      }
      const float inv = 1.f / sum;
      float o[8];
#pragma unroll
      for (int d = 0; d < 8; d++) o[d] = 0.f;
#pragma unroll
      for (int t = 0; t < kMR; t++) {
        const float w = sc[t] * inv;
        const int vb = (t * 16 + ub) * kQS + 64 + uh * 8;
#pragma unroll
        for (int d = 0; d < 8; d++) o[d] = fmaf(w, qkv[vb + d], o[d]);
      }
#pragma unroll
      for (int d = 0; d < 8; d++) qkv[base + d] = o[d];  // own q-slot
    }
    __syncthreads();
    // ---- out-proj: o-row -> xr (x is dead), 4 cols x 2 rows, new-x via K-slot
    {
      const float4* o0 = (const float4*)&qkv[row0 * kQS];
      const float4* o1 = (const float4*)&qkv[row1 * kQS];
#pragma unroll
      for (int j = 0; j < 8; j++) { xr[0][j] = o0[j]; xr[1][j] = o1[j]; }
    }
    float acc0[4], acc1[4];
#pragma unroll
    for (int ci = 0; ci < 4; ci++) {
      const int c2 = oct + 8 * ci;
      const float4* wr = (const float4*)&wo[c2 * 44];
      float a0 = 0.f, a1 = 0.f, a2 = 0.f, a3 = 0.f;
      float d0 = 0.f, d1 = 0.f, d2 = 0.f, d3 = 0.f;
#pragma unroll
      for (int j = 0; j < 8; j += 4) {
        float4 w0 = wr[j], w1 = wr[j+1], w2 = wr[j+2], w3 = wr[j+3];
        a0 = dot4(xr[0][j],   w0, a0);  d0 = dot4(xr[1][j],   w0, d0);
        a1 = dot4(xr[0][j+1], w1, a1);  d1 = dot4(xr[1][j+1], w1, d1);
        a2 = dot4(xr[0][j+2], w2, a2);  d2 = dot4(xr[1][j+2], w2, d2);
        a3 = dot4(xr[0][j+3], w3, a3);  d3 = dot4(xr[1][j+3], w3, d3);
      }
      const float bc = bo[c2];
      acc0[ci] = ((a0 + a1) + (a2 + a3)) + bc;
      acc1[ci] = ((d0 + d1) + (d2 + d3)) + bc;
    }
#pragma unroll
    for (int ci = 0; ci < 4; ci++) {
      qkv[row0 * kQS + 32 + oct + 8 * ci] = acc0[ci];   // dead K-slot
      qkv[row1 * kQS + 32 + oct + 8 * ci] = acc1[ci];
    }
    __syncthreads();
    if (l < kL - 1) {
      // reload new-x into registers for the next layer (compile-time j)
      const float4* n0 = (const float4*)&qkv[row0 * kQS + 32];
      const float4* n1 = (const float4*)&qkv[row1 * kQS + 32];
#pragma unroll
      for (int j = 0; j < 8; j++) { xr[0][j] = n0[j]; xr[1][j] = n1[j]; }
      __syncthreads();  // reload done before next staging/QKV writes
    }
  }
  // final write: cooperative coalesced copy from K-slot (no register array
  // runtime-indexing). xout[v*3072 + row*32 + h]; LDS addr row*100+32+h.
  for (int i = tid; i < 96 * 32; i += 384) {
    const int row = i >> 5, h = i & 31;
    xout[(size_t)v * (96 * 32) + i] = qkv[row * kQS + 32 + h];
  }
}

// ---------------- k3a: role-major logits, 2 pairs/thread -----------------
// block = (role r, g-chunk gc); 256 threads = 4 waves x (16 b x 4 slots).
// Wave w owns g-slice [125w,125w+125); thread handles 2 pairs so each
// 8x-float4 W-row read feeds 64 FMA. W rows stride-36 in LDS (16B aligned).
// g-loop unrolled x2 so the compiler pipelines next-g LDS reads under FMA.
__global__ __launch_bounds__(256) void k3a(const float* __restrict__ xw,
                                           const int* __restrict__ cnt,
                                           const int* __restrict__ pairs,
                                           const int* __restrict__ group_len,
                                           const float* __restrict__ Wn,
                                           const float* __restrict__ bn,
                                           float* __restrict__ PM,
                                           float* __restrict__ PS,
                                           float* __restrict__ PI) {
  __shared__ float Wl[kGCH * 36];
  __shared__ float Bl[kGCH];
  __shared__ float mbM[4][8][kB], mbS[4][8][kB], mbI[4][8][kB];
  const int r = blockIdx.x, gc = blockIdx.y;
  const int glen = group_len[r];
  const int g0 = gc * kGCH;
  if (g0 >= glen) return;
  int c = cnt[r]; if (c > kMAXP) c = kMAXP;
  if (c == 0) return;
  const int gn = (kGCH < glen - g0) ? kGCH : (glen - g0);
  const int tid = threadIdx.x;
  const float* W = Wn + (size_t)r * kH * kG + g0;
  const float* bias = bn + (size_t)r * kG + g0;
  for (int g = tid; g < gn; g += 256) {
#pragma unroll
    for (int h = 0; h < kH; h++) Wl[g * 36 + h] = W[(size_t)h * kG + g];
    Bl[g] = bias[g];
  }
  __syncthreads();
  const int wave = tid >> 6, lane = tid & 63;
  const int b = lane & 15, slot = lane >> 4;
  int gw0 = wave * 125, gw1 = gw0 + 125;
  gw0 = (gw0 < gn) ? gw0 : gn;
  gw1 = (gw1 < gn) ? gw1 : gn;
  const int nq = (c + 7) >> 3;
  for (int q = 0; q < nq; q++) {
    const int p0 = 8 * q + 2 * slot, p1 = p0 + 1;
    const bool v0 = p0 < c, v1 = p1 < c;
    const int pr0 = pairs[r * kMAXP + (v0 ? p0 : 0)];
    const int pr1 = pairs[r * kMAXP + (v1 ? p1 : 0)];
    float4 x0[8], x1[8];
    {
      const float4* xp0 = (const float4*)(xw + ((size_t)pr0 * kB + b) * kH);
      const float4* xp1 = (const float4*)(xw + ((size_t)pr1 * kB + b) * kH);
#pragma unroll
      for (int j = 0; j < 8; j++) { x0[j] = xp0[j]; x1[j] = xp1[j]; }
    }
    float m0 = -INFINITY, s0 = 0.f, m1 = -INFINITY, s1 = 0.f;
    int i0 = 0, i1 = 0;
#pragma unroll 2
    for (int g = gw0; g < gw1; g++) {
      const float4* wr = (const float4*)&Wl[g * 36];
      const float bg = Bl[g];
      float a0 = 0.f, a1 = 0.f, a2 = 0.f, a3 = 0.f;
      float c0 = 0.f, c1 = 0.f, c2 = 0.f, c3 = 0.f;
#pragma unroll
      for (int j = 0; j < 8; j += 4) {
        float4 w0 = wr[j], w1 = wr[j+1], w2 = wr[j+2], w3 = wr[j+3];
        a0 = dot4(x0[j],   w0, a0);  c0 = dot4(x1[j],   w0, c0);
        a1 = dot4(x0[j+1], w1, a1);  c1 = dot4(x1[j+1], w1, c1);
        a2 = dot4(x0[j+2], w2, a2);  c2 = dot4(x1[j+2], w2, c2);
        a3 = dot4(x0[j+3], w3, a3);  c3 = dot4(x1[j+3], w3, c3);
      }
      const float acc0 = ((a0 + a1) + (a2 + a3)) + bg;
      const float acc1 = ((c0 + c1) + (c2 + c3)) + bg;
      {
        float d = acc0 - m0; bool gt = d > 0.f;
        float e = __expf(gt ? -d : d);
        s0 = gt ? fmaf(s0, e, 1.f) : s0 + e;
        i0 = gt ? g0 + g : i0;  m0 = gt ? acc0 : m0;
      }
      {
        float d = acc1 - m1; bool gt = d > 0.f;
        float e = __expf(gt ? -d : d);
        s1 = gt ? fmaf(s1, e, 1.f) : s1 + e;
        i1 = gt ? g0 + g : i1;  m1 = gt ? acc1 : m1;
      }
    }
    mbM[wave][2*slot][b]   = v0 ? m0 : -INFINITY;
    mbS[wave][2*slot][b]   = s0;
    mbI[wave][2*slot][b]   = (float)i0;
    mbM[wave][2*slot+1][b] = v1 ? m1 : -INFINITY;
    mbS[wave][2*slot+1][b] = s1;
    mbI[wave][2*slot+1][b] = (float)i1;
    __syncthreads();
    if (tid < 128) {
      const int pl = tid >> 4, bb = tid & 15;
      const int pg = 8 * q + pl;
      if (pg < c) {
        float M = -INFINITY, S = 0.f; int I = 0;
#pragma unroll
        for (int w = 0; w < 4; w++) {
          float om = mbM[w][pl][bb];
          float os = mbS[w][pl][bb];
          int oi = (int)mbI[w][pl][bb];
          if (om != -INFINITY) {
            if (M == -INFINITY)      { M = om; S = os; I = oi; }
            else if (om > M)         { S = S * __expf(M - om) + os; M = om; I = oi; }
            else if (om < M)         { S = S + os * __expf(om - M); }
            else                     { S += os; I = (oi < I) ? oi : I; }
          }
        }
        const int pr2 = pairs[r * kMAXP + pg];
        size_t o = ((size_t)pr2 * kB + bb) * kGC + gc;
        PM[o] = M; PS[o] = S; PI[o] = (float)I;
      }
    }
    __syncthreads();
  }
}

// ---------------- k3b: merge g-chunk partials -> outputs -----------------
__device__ inline void lse_merge(float& m, float& s, int& i, float om, float os, int oi) {
  if (om == -INFINITY) return;
  if (m == -INFINITY) { m = om; s = os; i = oi; return; }
  if (om > m)       { s = s * __expf(m - om) + os; m = om; i = oi; }
  else if (om < m)  { s = s + os * __expf(om - m); }
  else              { s += os; i = (oi < i) ? oi : i; }
}

__global__ __launch_bounds__(256) void k3b(const int* __restrict__ verb_roles,
                                           const int* __restrict__ group_len,
                                           const float* __restrict__ PM,
                                           const float* __restrict__ PS,
                                           const float* __restrict__ PI,
                                           float* __restrict__ out) {
  const int idx = blockIdx.x * 256 + threadIdx.x;
  if (idx >= kV * kMR * kB) return;
  const int pr = idx >> 4;        // v*kMR + s
  const int b = idx & 15;
  const int v = pr / kMR, s = pr % kMR;
  const size_t o = ((size_t)b * kV + v) * kMR + s;
  const int r = verb_roles[pr];
  if (r < 0) {
    out[O_VRN + o] = 0.f; out[O_VRM + o] = 0.f; out[O_VRI + o] = 0.f;
    return;
  }
  const int glen = group_len[r];
  const int ngc = (glen + kGCH - 1) / kGCH;
  float M = -INFINITY, S = 0.f; int I = 0;
  for (int gc = 0; gc < ngc; gc++) {
    size_t po = ((size_t)pr * kB + b) * kGC + gc;
    lse_merge(M, S, I, PM[po], PS[po], (int)PI[po]);
  }
  out[O_VRN + o] = M + logf(S);
  out[O_VRM + o] = M;
  out[O_VRI + o] = (float)I;
}

// ---------------- k4: v_max, v_marginal LSE -> norm ----------------------
__global__ __launch_bounds__(256) void k4(float* __restrict__ out) {
  const int b = blockIdx.x;
  const int tid = threadIdx.x;
  float M = -INFINITY, S = 0.f;
  for (int v = tid; v < kV; v += 256) {
    float sm = 0.f, sx = 0.f;
#pragma unroll
    for (int s = 0; s < kMR; s++) {
      size_t o = ((size_t)b * kV + v) * kMR + s;
      sm += out[O_VRN + o];
      sx += out[O_VRM + o];
    }
    float vp = out[O_VPOT + (size_t)b * kV + v];
    float vm = sm + vp;
    out[O_VMAX + (size_t)b * kV + v] = sx + vp;
    float nm = fmaxf(M, vm);
    S = S * __expf(M - nm) + __expf(vm - nm);
    M = nm;
  }
#pragma unroll
  for (int off = 1; off < 64; off <<= 1) {
    float om = __shfl_xor(M, off);
    float os = __shfl_xor(S, off);
    if (om != -INFINITY) {
      if (M == -INFINITY) { M = om; S = os; }
      else if (om > M) { S = S * __expf(M - om) + os; M = om; }
      else { S += os * __expf(om - M); }
    }
  }
  __shared__ float rm2[4], rs2[4];
  const int wave = tid >> 6, lane = tid & 63;
  if (lane == 0) { rm2[wave] = M; rs2[wave] = S; }
  __syncthreads();
  if (tid == 0) {
    float Mm = rm2[0], Ss = rs2[0];
    for (int w = 1; w < 4; w++) {
      float om = rm2[w], os = rs2[w];
      if (om > Mm) { Ss = Ss * __expf(Mm - om) + os; Mm = om; }
      else { Ss += os * __expf(om - Mm); }
    }
    out[O_NORM + b] = Mm + logf(Ss);
  }
}

extern "C" void kernel_launch(void* const* d_in, const int* in_sizes, int n_in,
                              void* d_out, int out_size, void* d_ws, size_t ws_size,
                              hipStream_t stream) {
  const float* rep = (const float*)d_in[0];
  const float* Wv  = (const float*)d_in[1];
  const float* bv  = (const float*)d_in[2];
  const float* Wr  = (const float*)d_in[3];
  const float* br  = (const float*)d_in[4];
  const float* aiw = (const float*)d_in[5];
  const float* aib = (const float*)d_in[6];
  const float* aow = (const float*)d_in[7];
  const float* aob = (const float*)d_in[8];
  const float* Wn  = (const float*)d_in[9];
  const float* bnn = (const float*)d_in[10];
  const int* vrl   = (const int*)d_in[11];
  const int* gl    = (const int*)d_in[12];
  float* out = (float*)d_out;
  float* ws  = (float*)d_ws;
  int* icnt  = (int*)(ws + WS_CNT);
  int* ipair = (int*)(ws + WS_PAIR);

  k1a<<<dim3((kC1 + 255) / 256, kNDS), 256, 0, stream>>>(rep, Wv, Wr, ws + WS_PART);
  k1b<<<(kB * kC1 + 255) / 256, 256, 0, stream>>>(ws + WS_PART, bv, br, out, ws + WS_NODE);
  k0<<<1, 256, 0, stream>>>(vrl, icnt, ipair);
  k2<<<kV, 384, 0, stream>>>(ws + WS_NODE, vrl, aiw, aib, aow, aob, ws + WS_X);
  k3a<<<dim3(kR, kGC), 256, 0, stream>>>(ws + WS_X, icnt, ipair, gl, Wn, bnn,
                                         ws + WS_PM, ws + WS_PS, ws + WS_PI);
  k3b<<<(kV * kMR * kB + 255) / 256, 256, 0, stream>>>(vrl, gl, ws + WS_PM, ws + WS_PS,
                                                       ws + WS_PI, out);
  k4<<<kB, 256, 0, stream>>>(out);
}